// Round 13
// baseline (388.366 us; speedup 1.0000x reference)
//
#include <hip/hip_runtime.h>
#include <hip/hip_bf16.h>
#include <stdint.h>

typedef __attribute__((ext_vector_type(8))) short short8;
typedef __attribute__((ext_vector_type(4))) float floatx4;

#define DEVINL static __device__ __forceinline__

DEVINL float bfu(short v) {
  union { uint32_t i; float f; } x; x.i = ((uint32_t)(uint16_t)v) << 16; return x.f;
}
DEVINL uint16_t f2bf(float f) {
  union { float f; uint32_t i; } x; x.f = f;
  uint32_t i = x.i;
  i += 0x7fff + ((i >> 16) & 1);   // RNE
  return (uint16_t)(i >> 16);
}
DEVINL short8 u4s8(uint4 v) { union { uint4 u; short8 s; } x; x.u = v; return x.s; }

// ============ fused prep: fp32->bf16 cvt of x + both weight transposes ============
DEVINL void transpose_tile(const float* in, uint16_t* out, int K, int N,
                           int bx, int by, float (*tile)[65]) {
  const int tn = bx * 64;
  const int tk = by * 64;
  const int tx = threadIdx.x & 63;
  const int ty = threadIdx.x >> 6;   // 0..3
#pragma unroll
  for (int i = 0; i < 64; i += 4)
    tile[ty + i][tx] = in[(long)(tk + ty + i) * N + tn + tx];
  __syncthreads();
#pragma unroll
  for (int i = 0; i < 64; i += 4)
    out[(long)(tn + ty + i) * K + tk + tx] = f2bf(tile[tx][ty + i]);
}

__global__ __launch_bounds__(256)
void k_prep(const float* __restrict__ x, uint16_t* __restrict__ x_bf, int n4,
            const float* __restrict__ w_qkv, uint16_t* __restrict__ wqkvT,
            const float* __restrict__ w_proj, uint16_t* __restrict__ wprojT) {
  __shared__ float tile[64][65];
  const int bid = blockIdx.x;
  if (bid < 2048) {
    int i = bid * 256 + threadIdx.x;
    const int stride = 2048 * 256;
    for (; i < n4; i += stride) {
      float4 v = ((const float4*)x)[i];
      ushort4 o;
      o.x = f2bf(v.x); o.y = f2bf(v.y); o.z = f2bf(v.z); o.w = f2bf(v.w);
      ((ushort4*)x_bf)[i] = o;
    }
  } else if (bid < 2048 + 36 * 12) {
    const int tq = bid - 2048;
    transpose_tile(w_qkv, wqkvT, 768, 2304, tq % 36, tq / 36, tile);
  } else {
    const int tp = bid - (2048 + 36 * 12);
    transpose_tile(w_proj, wprojT, 768, 768, tp % 12, tp / 12, tile);
  }
}

// ============ GEMM1: 128x128, A via gload_lds, B via REGISTERS (R13) ============
// LDS = As only (32 KB). Ledger (vmcnt FIFO, per tile kt):
//   carry-in: A_lo(t1) 2
//   issue: a-reads(8, lgkm) ; A_hi(t1)->nbuf 2 ; Breg(t1) 8 ; lgkm(0) ; c1 ;
//          BAR ; A_lo(t2)->cbuf 2 ; c2 ; vmcnt(2) [oldest 12 = A(t1)+Breg(t1)] ; BAR
// Prologue order: A_lo(0),A_hi(0),Breg(0)x8,A_lo(1) => vmcnt(2).
// B frag loaded per-lane directly in MFMA layout (row wn*64+nn*16+fr,
// col kt*64+kk*32+kg*8) — no swizzle needed, B panel is L2-hot.
__global__ __launch_bounds__(256, 2)
void k_gemm1b(const uint16_t* __restrict__ A,   // [M][Kd] bf16
              const uint16_t* __restrict__ B,   // [N][Kd] bf16
              uint16_t* __restrict__ Cout,      // bf16 [M][N]
              int M, int N, int Kd, int tilesN)
{
  __shared__ uint16_t As[2][2][4096];  // [buf][half(64 rows)][64 x 64]

  const int nwg = gridDim.x;
  const int orig = blockIdx.x;
  const int q = nwg >> 3, r = nwg & 7;
  const int xcd = orig & 7, seq = orig >> 3;
  const int wgid = (xcd < r ? xcd * (q + 1) : r * (q + 1) + (xcd - r) * q) + seq;
  const int mt = wgid / tilesN;
  const int nt = wgid - mt * tilesN;

  const int t = threadIdx.x;
  const int l = t & 63;
  const int w = t >> 6;                // 0..3
  const int wm = w >> 1;               // 0..1
  const int wn = w & 1;                // 0..1
  const long m0 = (long)mt * 128;
  const long n0 = (long)nt * 128;

  const int srow0 = t >> 3;            // 0..31
  const int scol  = ((l & 7) ^ (l >> 3)) * 8;
  const int wbyte = w * 1024;

  const uint16_t* Abase = A + m0 * Kd;

  const int fr = l & 15;
  const int kg = l >> 4;
  const int xorv = (l & 7) << 4;
  const int cb0 = (kg * 16) ^ xorv;
  const int cb1 = (64 + kg * 16) ^ xorv;

  // per-lane B fragment base (unswizzled, direct MFMA layout)
  const uint16_t* Blane = B + (n0 + wn * 64 + fr) * Kd + kg * 8;

  floatx4 acc[4][4];
#pragma unroll
  for (int m = 0; m < 4; ++m)
#pragma unroll
    for (int n = 0; n < 4; ++n)
      acc[m][n] = (floatx4){0.f, 0.f, 0.f, 0.f};

  const int nK = Kd >> 6;   // 12 (even)

  auto stage = [&](uint16_t* ldsHalf, const uint16_t* gHalf, int ktile) {
    const uint16_t* g0 = gHalf + (long)srow0 * Kd + ktile * 64 + scol;
    __builtin_amdgcn_global_load_lds(
        (const __attribute__((address_space(1))) void*)g0,
        (__attribute__((address_space(3))) void*)((char*)ldsHalf + wbyte), 16, 0, 0);
    __builtin_amdgcn_global_load_lds(
        (const __attribute__((address_space(1))) void*)(g0 + (long)32 * Kd),
        (__attribute__((address_space(3))) void*)((char*)ldsHalf + 4096 + wbyte), 16, 0, 0);
  };
  auto rdA = [&](int buf, int mm, int kk) -> short8 {
    const char* p = (const char*)&As[buf][wm][0] + mm * 2048 + fr * 128 + (kk ? cb1 : cb0);
    return *(const short8*)p;
  };

  short8 a[4][2];
  uint4 bp[8], bq[8];   // B frag sets: frag (nn,kk) at index nn*2+kk

#define LOADB(DST, KT) do {                                                  \
    const uint16_t* gB_ = Blane + (long)(KT) * 64;                           \
    _Pragma("unroll")                                                        \
    for (int nn_ = 0; nn_ < 4; ++nn_) {                                      \
      DST[nn_ * 2]     = *(const uint4*)(gB_ + (long)nn_ * 16 * Kd);         \
      DST[nn_ * 2 + 1] = *(const uint4*)(gB_ + (long)nn_ * 16 * Kd + 32);    \
    }                                                                        \
  } while (0)

#define TILE(CBUF, KT, BU, BL) do {                                          \
    const int t1_ = ((KT) + 1) % nK;                                         \
    const int t2_ = ((KT) + 2) % nK;                                         \
    _Pragma("unroll")                                                        \
    for (int mm_ = 0; mm_ < 4; ++mm_) {                                      \
      a[mm_][0] = rdA(CBUF, mm_, 0); a[mm_][1] = rdA(CBUF, mm_, 1);          \
    }                                                                        \
    stage(&As[(CBUF) ^ 1][1][0], Abase + (long)64 * Kd, t1_);                \
    LOADB(BL, t1_);                                                          \
    asm volatile("s_waitcnt lgkmcnt(0)" ::: "memory");                       \
    __builtin_amdgcn_s_setprio(1);                                          \
    _Pragma("unroll")                                                        \
    for (int mm_ = 0; mm_ < 4; ++mm_)                                        \
      _Pragma("unroll")                                                      \
      for (int nn_ = 0; nn_ < 2; ++nn_) {                                    \
        acc[mm_][nn_] = __builtin_amdgcn_mfma_f32_16x16x32_bf16(             \
            a[mm_][0], u4s8(BU[nn_ * 2]), acc[mm_][nn_], 0, 0, 0);           \
        acc[mm_][nn_] = __builtin_amdgcn_mfma_f32_16x16x32_bf16(             \
            a[mm_][1], u4s8(BU[nn_ * 2 + 1]), acc[mm_][nn_], 0, 0, 0);       \
      }                                                                      \
    __builtin_amdgcn_s_barrier();                                           \
    stage(&As[CBUF][0][0], Abase, t2_);                                      \
    _Pragma("unroll")                                                        \
    for (int mm_ = 0; mm_ < 4; ++mm_)                                        \
      _Pragma("unroll")                                                      \
      for (int nn_ = 0; nn_ < 2; ++nn_) {                                    \
        acc[mm_][2 + nn_] = __builtin_amdgcn_mfma_f32_16x16x32_bf16(         \
            a[mm_][0], u4s8(BU[(2 + nn_) * 2]), acc[mm_][2 + nn_], 0, 0, 0); \
        acc[mm_][2 + nn_] = __builtin_amdgcn_mfma_f32_16x16x32_bf16(         \
            a[mm_][1], u4s8(BU[(2 + nn_) * 2 + 1]), acc[mm_][2 + nn_], 0, 0, 0); \
      }                                                                      \
    __builtin_amdgcn_s_setprio(0);                                          \
    asm volatile("s_waitcnt vmcnt(2)" ::: "memory");                         \
    __builtin_amdgcn_s_barrier();                                           \
  } while (0)

  // ---- prologue: A_lo(0), A_hi(0), Breg(0)x8, A_lo(1); vmcnt(2) ----
  stage(&As[0][0][0], Abase, 0);
  stage(&As[0][1][0], Abase + (long)64 * Kd, 0);
  LOADB(bp, 0);
  stage(&As[1][0][0], Abase, 1 % nK);
  asm volatile("s_waitcnt vmcnt(2)" ::: "memory");
  __builtin_amdgcn_s_barrier();

  for (int kt2 = 0; kt2 < nK; kt2 += 2) {
    TILE(0, kt2, bp, bq);
    TILE(1, kt2 + 1, bq, bp);
  }
#undef TILE
#undef LOADB

  // drain wrapped tail stages (they write As)
  asm volatile("s_waitcnt vmcnt(0)" ::: "memory");
  __builtin_amdgcn_s_barrier();

  // LDS-staged coalesced bf16 epilogue (C/D: col=lane&15, row=(lane>>4)*4+reg)
  const int orow = (l >> 4) * 4;
  const int ocol = l & 15;
  {
    char* eb = (char*)&As[0][0][0] + (size_t)w * 4096;   // wave-private 4KB
    const int rr0 = l >> 3;
    const int cc0 = (l & 7) * 8;
#pragma unroll
    for (int mm = 0; mm < 4; ++mm) {
#pragma unroll
      for (int nn = 0; nn < 4; ++nn)
#pragma unroll
        for (int r2 = 0; r2 < 4; ++r2) {
          int rrow = orow + r2;
          int byo = ((rrow * 64 + nn * 16 + ocol) * 2) ^ ((rrow & 7) << 4);
          *(uint16_t*)(eb + byo) = f2bf(acc[mm][nn][r2]);
        }
#pragma unroll
      for (int p = 0; p < 2; ++p) {
        int rrow = rr0 + p * 8;
        int byo = ((rrow * 64 + cc0) * 2) ^ ((rrow & 7) << 4);
        short8 vvv = *(const short8*)(eb + byo);
        *(short8*)(&Cout[(m0 + wm * 64 + mm * 16 + rrow) * N + n0 + wn * 64 + cc0]) = vvv;
      }
    }
  }
}

// ============ 128x128 bf16 GEMM (R12 EXACT), C = A @ B^T — GEMM2 ============
template<int OUT_BF16>
__global__ __launch_bounds__(256, 2)
void k_gemm128(const uint16_t* __restrict__ A,   // [M][Kd] bf16
               const uint16_t* __restrict__ B,   // [N][Kd] bf16
               void* __restrict__ Cout,          // bf16 [M][N] or fp32 [M][N]
               const float* __restrict__ bias,   // nullable (fp32 path)
               int M, int N, int Kd, int tilesN)
{
  __shared__ uint16_t As[2][2][4096];
  __shared__ uint16_t Bs[2][2][4096];

  const int nwg = gridDim.x;
  const int orig = blockIdx.x;
  const int q = nwg >> 3, r = nwg & 7;
  const int xcd = orig & 7, seq = orig >> 3;
  const int wgid = (xcd < r ? xcd * (q + 1) : r * (q + 1) + (xcd - r) * q) + seq;
  const int mt = wgid / tilesN;
  const int nt = wgid - mt * tilesN;

  const int t = threadIdx.x;
  const int l = t & 63;
  const int w = t >> 6;
  const int wm = w >> 1;
  const int wn = w & 1;
  const long m0 = (long)mt * 128;
  const long n0 = (long)nt * 128;

  const int srow0 = t >> 3;
  const int scol  = ((l & 7) ^ (l >> 3)) * 8;
  const int wbyte = w * 1024;

  const uint16_t* Abase = A + m0 * Kd;
  const uint16_t* Bbase = B + n0 * Kd;

  const int fr = l & 15;
  const int kg = l >> 4;
  const int xorv = (l & 7) << 4;
  const int cb0 = (kg * 16) ^ xorv;
  const int cb1 = (64 + kg * 16) ^ xorv;

  floatx4 acc[4][4];
#pragma unroll
  for (int m = 0; m < 4; ++m)
#pragma unroll
    for (int n = 0; n < 4; ++n)
      acc[m][n] = (floatx4){0.f, 0.f, 0.f, 0.f};

  const int nK = Kd >> 6;

  auto stage = [&](uint16_t* ldsHalf, const uint16_t* gHalf, int ktile) {
    const uint16_t* g0 = gHalf + (long)srow0 * Kd + ktile * 64 + scol;
    __builtin_amdgcn_global_load_lds(
        (const __attribute__((address_space(1))) void*)g0,
        (__attribute__((address_space(3))) void*)((char*)ldsHalf + wbyte), 16, 0, 0);
    __builtin_amdgcn_global_load_lds(
        (const __attribute__((address_space(1))) void*)(g0 + (long)32 * Kd),
        (__attribute__((address_space(3))) void*)((char*)ldsHalf + 4096 + wbyte), 16, 0, 0);
  };
  auto rdA = [&](int buf, int mm, int kk) -> short8 {
    const char* p = (const char*)&As[buf][wm][0] + mm * 2048 + fr * 128 + (kk ? cb1 : cb0);
    return *(const short8*)p;
  };
  auto rdB = [&](int buf, int nn, int kk) -> short8 {
    const char* p = (const char*)&Bs[buf][wn][0] + nn * 2048 + fr * 128 + (kk ? cb1 : cb0);
    return *(const short8*)p;
  };

  stage(&Bs[0][0][0], Bbase, 0);
  stage(&Bs[0][1][0], Bbase + (long)64 * Kd, 0);
  stage(&As[0][0][0], Abase, 0);
  stage(&As[0][1][0], Abase + (long)64 * Kd, 0);
  {
    int t1 = 1 % nK;
    stage(&Bs[t1 & 1][0][0], Bbase, t1);
    stage(&As[t1 & 1][0][0], Abase, t1);
  }
  asm volatile("s_waitcnt vmcnt(4)" ::: "memory");
  __builtin_amdgcn_s_barrier();

  short8 a[4][2], bv0[2][2], bv1[2][2];

  for (int kt = 0; kt < nK; ++kt) {
    const int cbuf = kt & 1;
    const int nbuf = cbuf ^ 1;
    const int t1 = (kt + 1) % nK;
    const int t2 = (kt + 2) % nK;

#pragma unroll
    for (int mm = 0; mm < 4; ++mm) { a[mm][0] = rdA(cbuf, mm, 0); a[mm][1] = rdA(cbuf, mm, 1); }
#pragma unroll
    for (int nn = 0; nn < 2; ++nn) { bv0[nn][0] = rdB(cbuf, nn, 0); bv0[nn][1] = rdB(cbuf, nn, 1); }
#pragma unroll
    for (int nn = 0; nn < 2; ++nn) { bv1[nn][0] = rdB(cbuf, 2 + nn, 0); bv1[nn][1] = rdB(cbuf, 2 + nn, 1); }

    stage(&Bs[nbuf][1][0], Bbase + (long)64 * Kd, t1);
    stage(&As[nbuf][1][0], Abase + (long)64 * Kd, t1);

    asm volatile("s_waitcnt lgkmcnt(4)" ::: "memory");
    __builtin_amdgcn_s_setprio(1);
#pragma unroll
    for (int mm = 0; mm < 4; ++mm)
#pragma unroll
      for (int nn = 0; nn < 2; ++nn) {
        acc[mm][nn] = __builtin_amdgcn_mfma_f32_16x16x32_bf16(a[mm][0], bv0[nn][0], acc[mm][nn], 0, 0, 0);
        acc[mm][nn] = __builtin_amdgcn_mfma_f32_16x16x32_bf16(a[mm][1], bv0[nn][1], acc[mm][nn], 0, 0, 0);
      }
    asm volatile("s_waitcnt lgkmcnt(0)" ::: "memory");
    __builtin_amdgcn_s_barrier();

    stage(&Bs[cbuf][0][0], Bbase, t2);
    stage(&As[cbuf][0][0], Abase, t2);
#pragma unroll
    for (int mm = 0; mm < 4; ++mm)
#pragma unroll
      for (int nn = 0; nn < 2; ++nn) {
        acc[mm][2 + nn] = __builtin_amdgcn_mfma_f32_16x16x32_bf16(a[mm][0], bv1[nn][0], acc[mm][2 + nn], 0, 0, 0);
        acc[mm][2 + nn] = __builtin_amdgcn_mfma_f32_16x16x32_bf16(a[mm][1], bv1[nn][1], acc[mm][2 + nn], 0, 0, 0);
      }
    __builtin_amdgcn_s_setprio(0);

    asm volatile("s_waitcnt vmcnt(4)" ::: "memory");
    __builtin_amdgcn_s_barrier();
  }

  asm volatile("s_waitcnt vmcnt(0)" ::: "memory");
  __builtin_amdgcn_s_barrier();

  const int orow = (l >> 4) * 4;
  const int ocol = l & 15;
  if (OUT_BF16) {
    uint16_t* C = (uint16_t*)Cout;
    char* eb = (char*)&As[0][0][0] + (size_t)w * 4096;
    const int rr0 = l >> 3;
    const int cc0 = (l & 7) * 8;
#pragma unroll
    for (int mm = 0; mm < 4; ++mm) {
#pragma unroll
      for (int nn = 0; nn < 4; ++nn)
#pragma unroll
        for (int r2 = 0; r2 < 4; ++r2) {
          int rrow = orow + r2;
          int byo = ((rrow * 64 + nn * 16 + ocol) * 2) ^ ((rrow & 7) << 4);
          *(uint16_t*)(eb + byo) = f2bf(acc[mm][nn][r2]);
        }
#pragma unroll
      for (int p = 0; p < 2; ++p) {
        int rrow = rr0 + p * 8;
        int byo = ((rrow * 64 + cc0) * 2) ^ ((rrow & 7) << 4);
        short8 vvv = *(const short8*)(eb + byo);
        *(short8*)(&C[(m0 + wm * 64 + mm * 16 + rrow) * N + n0 + wn * 64 + cc0]) = vvv;
      }
    }
  } else {
    float* C = (float*)Cout;
    float* eb = (float*)&As[0][0][0] + (size_t)w * 1024;
    const int rr0 = l >> 4;
    const int cc0 = (l & 15) * 4;
    float4 bias4 = make_float4(0.f, 0.f, 0.f, 0.f);
    if (bias) bias4 = *(const float4*)(bias + n0 + wn * 64 + cc0);
#pragma unroll
    for (int mm = 0; mm < 4; ++mm) {
#pragma unroll
      for (int nn = 0; nn < 4; ++nn)
#pragma unroll
        for (int r2 = 0; r2 < 4; ++r2)
          eb[(orow + r2) * 64 + nn * 16 + ocol] = acc[mm][nn][r2];
#pragma unroll
      for (int p = 0; p < 4; ++p) {
        int rrow = rr0 + p * 4;
        float4 vvv = *(const float4*)(eb + rrow * 64 + cc0);
        vvv.x += bias4.x; vvv.y += bias4.y; vvv.z += bias4.z; vvv.w += bias4.w;
        *(float4*)(&C[(m0 + wm * 64 + mm * 16 + rrow) * N + n0 + wn * 64 + cc0]) = vvv;
      }
    }
  }
}

// ---------------- per-token 6-head attention, 16 lanes per token ----------------
__global__ __launch_bounds__(256)
void k_attn(const uint16_t* __restrict__ qkv, uint16_t* __restrict__ outp) {
  const int wid = blockIdx.x * 4 + (threadIdx.x >> 6);
  const int l = threadIdx.x & 63;
  const int sub = l >> 4;
  const int i = l & 15;
  const int token = wid * 4 + sub;
  const uint16_t* row = qkv + (long)token * 2304 + i * 8;

  short8 kv[6];
  float qf[6][8];
#pragma unroll
  for (int h = 0; h < 6; ++h) {
    short8 qv = *(const short8*)(row + h * 128);
    kv[h] = *(const short8*)(row + 768 + h * 128);
#pragma unroll
    for (int e = 0; e < 8; ++e) qf[h][e] = bfu(qv[e]);
  }

  float s[36];
#pragma unroll
  for (int g = 0; g < 6; ++g) {
    float kf[8];
#pragma unroll
    for (int e = 0; e < 8; ++e) kf[e] = bfu(kv[g][e]);
#pragma unroll
    for (int h = 0; h < 6; ++h) {
      float a = 0.f;
#pragma unroll
      for (int e = 0; e < 8; ++e) a += qf[h][e] * kf[e];
      s[h * 6 + g] = a;
    }
  }

#pragma unroll
  for (int off = 8; off > 0; off >>= 1)
#pragma unroll
    for (int j = 0; j < 36; ++j)
      s[j] += __shfl_xor(s[j], off, 64);

  const float scale = 0.088388347648318447f;  // 128^-0.5
  float p[36];
#pragma unroll
  for (int h = 0; h < 6; ++h) {
    float mx = s[h * 6];
#pragma unroll
    for (int g = 1; g < 6; ++g) mx = fmaxf(mx, s[h * 6 + g]);
    float sum = 0.f;
#pragma unroll
    for (int g = 0; g < 6; ++g) {
      float e = __expf((s[h * 6 + g] - mx) * scale);
      p[h * 6 + g] = e; sum += e;
    }
    float inv = 1.f / sum;
#pragma unroll
    for (int g = 0; g < 6; ++g) p[h * 6 + g] *= inv;
  }

  float o[6][8];
#pragma unroll
  for (int h = 0; h < 6; ++h)
#pragma unroll
    for (int e = 0; e < 8; ++e) o[h][e] = 0.f;
#pragma unroll
  for (int g = 0; g < 6; ++g) {
    short8 vv = *(const short8*)(row + 1536 + g * 128);
    float vf[8];
#pragma unroll
    for (int e = 0; e < 8; ++e) vf[e] = bfu(vv[e]);
#pragma unroll
    for (int h = 0; h < 6; ++h)
#pragma unroll
      for (int e = 0; e < 8; ++e) o[h][e] += p[h * 6 + g] * vf[e];
  }

  const int b = token >> 12, nn = token & 4095;
#pragma unroll
  for (int h = 0; h < 6; ++h) {
    short8 ov;
#pragma unroll
    for (int e = 0; e < 8; ++e) ov[e] = (short)f2bf(o[h][e]);
    *(short8*)(outp + ((long)(b * 6 + h) * 4096 + nn) * 128 + i * 8) = ov;
  }
}

extern "C" void kernel_launch(void* const* d_in, const int* in_sizes, int n_in,
                              void* d_out, int out_size, void* d_ws, size_t ws_size,
                              hipStream_t stream) {
  const float* x      = (const float*)d_in[0];
  const float* w_qkv  = (const float*)d_in[1];
  const float* w_proj = (const float*)d_in[2];
  const float* b_proj = (const float*)d_in[3];
  float* out = (float*)d_out;

  const int Cc = 768, C3 = 2304;
  const int Mtok = in_sizes[0] / Cc;  // 32768

  char* ws = (char*)d_ws;
  uint16_t* x_bf   = (uint16_t*)ws;                            // 50,331,648 B
  uint16_t* att_bf = x_bf;                                     // reuse (x_bf dead after GEMM1)
  uint16_t* qkv_bf = (uint16_t*)(ws + 50331648);               // 150,994,944 B
  uint16_t* wqkvT  = (uint16_t*)(ws + 50331648 + 150994944);   // 3,538,944 B
  uint16_t* wprojT = (uint16_t*)(ws + 50331648 + 150994944 + 3538944); // 1,179,648 B

  hipLaunchKernelGGL(k_prep, dim3(2048 + 432 + 144), dim3(256), 0, stream,
                     x, x_bf, Mtok * Cc / 4, w_qkv, wqkvT, w_proj, wprojT);

  // GEMM1 (B-in-reg): 256 x 18 = 4608 blocks
  hipLaunchKernelGGL(k_gemm1b, dim3((Mtok / 128) * (C3 / 128)), dim3(256), 0, stream,
                     x_bf, wqkvT, qkv_bf, Mtok, C3, Cc, C3 / 128);

  hipLaunchKernelGGL(k_attn, dim3(Mtok / 16), dim3(256), 0, stream, qkv_bf, att_bf);

  // GEMM2 (R12 exact): 1536 blocks
  hipLaunchKernelGGL((k_gemm128<0>), dim3((Mtok / 128) * (Cc / 128)), dim3(256), 0, stream,
                     att_bf, wprojT, (void*)out, b_proj, Mtok, Cc, Cc, Cc / 128);
}

// Round 14
// 244.726 us; speedup vs baseline: 1.5869x; 1.5869x over previous
//
#include <hip/hip_runtime.h>
#include <hip/hip_bf16.h>
#include <stdint.h>

typedef __attribute__((ext_vector_type(8))) short short8;
typedef __attribute__((ext_vector_type(4))) float floatx4;

#define DEVINL static __device__ __forceinline__

DEVINL float bfu(short v) {
  union { uint32_t i; float f; } x; x.i = ((uint32_t)(uint16_t)v) << 16; return x.f;
}
DEVINL uint16_t f2bf(float f) {
  union { float f; uint32_t i; } x; x.f = f;
  uint32_t i = x.i;
  i += 0x7fff + ((i >> 16) & 1);   // RNE
  return (uint16_t)(i >> 16);
}

// ============ fused prep: fp32->bf16 cvt of x + both weight transposes ============
DEVINL void transpose_tile(const float* in, uint16_t* out, int K, int N,
                           int bx, int by, float (*tile)[65]) {
  const int tn = bx * 64;
  const int tk = by * 64;
  const int tx = threadIdx.x & 63;
  const int ty = threadIdx.x >> 6;   // 0..3
#pragma unroll
  for (int i = 0; i < 64; i += 4)
    tile[ty + i][tx] = in[(long)(tk + ty + i) * N + tn + tx];
  __syncthreads();
#pragma unroll
  for (int i = 0; i < 64; i += 4)
    out[(long)(tn + ty + i) * K + tk + tx] = f2bf(tile[tx][ty + i]);
}

__global__ __launch_bounds__(256)
void k_prep(const float* __restrict__ x, uint16_t* __restrict__ x_bf, int n4,
            const float* __restrict__ w_qkv, uint16_t* __restrict__ wqkvT,
            const float* __restrict__ w_proj, uint16_t* __restrict__ wprojT) {
  __shared__ float tile[64][65];
  const int bid = blockIdx.x;
  if (bid < 2048) {
    int i = bid * 256 + threadIdx.x;
    const int stride = 2048 * 256;
    for (; i < n4; i += stride) {
      float4 v = ((const float4*)x)[i];
      ushort4 o;
      o.x = f2bf(v.x); o.y = f2bf(v.y); o.z = f2bf(v.z); o.w = f2bf(v.w);
      ((ushort4*)x_bf)[i] = o;
    }
  } else if (bid < 2048 + 36 * 12) {
    const int tq = bid - 2048;
    transpose_tile(w_qkv, wqkvT, 768, 2304, tq % 36, tq / 36, tile);
  } else {
    const int tp = bid - (2048 + 36 * 12);
    transpose_tile(w_proj, wprojT, 768, 768, tp % 12, tp / 12, tile);
  }
}

// ============ 128x128 bf16 GEMM (R12 EXACT), C = A @ B^T (B stored [N][K]) ============
// 2 blocks/CU (64 KB LDS). Ledger (R7-derived, verified):
//   prologue: t0 full [B_lo,B_hi,A_lo,A_hi]=8 + B_lo(t1),A_lo(t1)=4 ; vmcnt(4)
//   loop kt:  16 ds_reads (a:8, bv0:4, bv1:4) ;
//             early stage B_hi(t1),A_hi(t1)->nbuf (4) ;
//             lgkm(4) ; MFMA c1 (16) ; lgkm(0) ; BARRIER ;
//             mid stage B_lo(t2),A_lo(t2)->cbuf (4) ; MFMA c2 (16) ;
//             vmcnt(4) [queue 12, oldest 8 = tile t1 complete] ; BARRIER.
// T2 swizzle (row&7)<<4 both-sides; T5 setprio; XCD-bijective remap (m204).
template<int OUT_BF16>
__global__ __launch_bounds__(256, 2)
void k_gemm128(const uint16_t* __restrict__ A,   // [M][Kd] bf16
               const uint16_t* __restrict__ B,   // [N][Kd] bf16
               void* __restrict__ Cout,          // bf16 [M][N] or fp32 [M][N]
               const float* __restrict__ bias,   // nullable (fp32 path)
               int M, int N, int Kd, int tilesN)
{
  __shared__ uint16_t As[2][2][4096];  // [buf][half(64 rows)][64 x 64]
  __shared__ uint16_t Bs[2][2][4096];

  const int nwg = gridDim.x;
  const int orig = blockIdx.x;
  const int q = nwg >> 3, r = nwg & 7;
  const int xcd = orig & 7, seq = orig >> 3;
  const int wgid = (xcd < r ? xcd * (q + 1) : r * (q + 1) + (xcd - r) * q) + seq;
  const int mt = wgid / tilesN;
  const int nt = wgid - mt * tilesN;

  const int t = threadIdx.x;           // 0..255
  const int l = t & 63;
  const int w = t >> 6;                // 0..3
  const int wm = w >> 1;               // 0..1
  const int wn = w & 1;                // 0..1
  const long m0 = (long)mt * 128;
  const long n0 = (long)nt * 128;

  const int srow0 = t >> 3;            // 0..31
  const int scol  = ((l & 7) ^ (l >> 3)) * 8;
  const int wbyte = w * 1024;

  const uint16_t* Abase = A + m0 * Kd;
  const uint16_t* Bbase = B + n0 * Kd;

  const int fr = l & 15;
  const int kg = l >> 4;
  const int xorv = (l & 7) << 4;
  const int cb0 = (kg * 16) ^ xorv;
  const int cb1 = (64 + kg * 16) ^ xorv;

  floatx4 acc[4][4];
#pragma unroll
  for (int m = 0; m < 4; ++m)
#pragma unroll
    for (int n = 0; n < 4; ++n)
      acc[m][n] = (floatx4){0.f, 0.f, 0.f, 0.f};

  const int nK = Kd >> 6;   // 12 (even)

  auto stage = [&](uint16_t* ldsHalf, const uint16_t* gHalf, int ktile) {
    const uint16_t* g0 = gHalf + (long)srow0 * Kd + ktile * 64 + scol;
    __builtin_amdgcn_global_load_lds(
        (const __attribute__((address_space(1))) void*)g0,
        (__attribute__((address_space(3))) void*)((char*)ldsHalf + wbyte), 16, 0, 0);
    __builtin_amdgcn_global_load_lds(
        (const __attribute__((address_space(1))) void*)(g0 + (long)32 * Kd),
        (__attribute__((address_space(3))) void*)((char*)ldsHalf + 4096 + wbyte), 16, 0, 0);
  };
  auto rdA = [&](int buf, int mm, int kk) -> short8 {
    const char* p = (const char*)&As[buf][wm][0] + mm * 2048 + fr * 128 + (kk ? cb1 : cb0);
    return *(const short8*)p;
  };
  auto rdB = [&](int buf, int nn, int kk) -> short8 {
    const char* p = (const char*)&Bs[buf][wn][0] + nn * 2048 + fr * 128 + (kk ? cb1 : cb0);
    return *(const short8*)p;
  };

  // ---- prologue ----
  stage(&Bs[0][0][0], Bbase, 0);
  stage(&Bs[0][1][0], Bbase + (long)64 * Kd, 0);
  stage(&As[0][0][0], Abase, 0);
  stage(&As[0][1][0], Abase + (long)64 * Kd, 0);
  {
    int t1 = 1 % nK;
    stage(&Bs[t1 & 1][0][0], Bbase, t1);
    stage(&As[t1 & 1][0][0], Abase, t1);
  }
  asm volatile("s_waitcnt vmcnt(4)" ::: "memory");
  __builtin_amdgcn_s_barrier();

  short8 a[4][2], bv0[2][2], bv1[2][2];

  for (int kt = 0; kt < nK; ++kt) {
    const int cbuf = kt & 1;
    const int nbuf = cbuf ^ 1;
    const int t1 = (kt + 1) % nK;
    const int t2 = (kt + 2) % nK;

    // 16 cbuf ds_reads: a (8), bv0 (4), bv1 (4) — reads first (R9 lesson)
#pragma unroll
    for (int mm = 0; mm < 4; ++mm) { a[mm][0] = rdA(cbuf, mm, 0); a[mm][1] = rdA(cbuf, mm, 1); }
#pragma unroll
    for (int nn = 0; nn < 2; ++nn) { bv0[nn][0] = rdB(cbuf, nn, 0); bv0[nn][1] = rdB(cbuf, nn, 1); }
#pragma unroll
    for (int nn = 0; nn < 2; ++nn) { bv1[nn][0] = rdB(cbuf, 2 + nn, 0); bv1[nn][1] = rdB(cbuf, 2 + nn, 1); }

    // early 2-deep stage: t1 upper halves -> nbuf (never read this K-tile)
    stage(&Bs[nbuf][1][0], Bbase + (long)64 * Kd, t1);
    stage(&As[nbuf][1][0], Abase + (long)64 * Kd, t1);

    asm volatile("s_waitcnt lgkmcnt(4)" ::: "memory");   // first 12 reads done
    __builtin_amdgcn_s_setprio(1);
#pragma unroll
    for (int mm = 0; mm < 4; ++mm)
#pragma unroll
      for (int nn = 0; nn < 2; ++nn) {
        acc[mm][nn] = __builtin_amdgcn_mfma_f32_16x16x32_bf16(a[mm][0], bv0[nn][0], acc[mm][nn], 0, 0, 0);
        acc[mm][nn] = __builtin_amdgcn_mfma_f32_16x16x32_bf16(a[mm][1], bv0[nn][1], acc[mm][nn], 0, 0, 0);
      }
    asm volatile("s_waitcnt lgkmcnt(0)" ::: "memory");
    __builtin_amdgcn_s_barrier();   // all waves done reading cbuf

    // mid stage: t2 lower halves -> cbuf; overlaps MFMA c2
    stage(&Bs[cbuf][0][0], Bbase, t2);
    stage(&As[cbuf][0][0], Abase, t2);
#pragma unroll
    for (int mm = 0; mm < 4; ++mm)
#pragma unroll
      for (int nn = 0; nn < 2; ++nn) {
        acc[mm][2 + nn] = __builtin_amdgcn_mfma_f32_16x16x32_bf16(a[mm][0], bv1[nn][0], acc[mm][2 + nn], 0, 0, 0);
        acc[mm][2 + nn] = __builtin_amdgcn_mfma_f32_16x16x32_bf16(a[mm][1], bv1[nn][1], acc[mm][2 + nn], 0, 0, 0);
      }
    __builtin_amdgcn_s_setprio(0);

    // gate: queue 12, oldest 8 = tile t1 fully resident => vmcnt(4)
    asm volatile("s_waitcnt vmcnt(4)" ::: "memory");
    __builtin_amdgcn_s_barrier();
  }

  // drain wrapped tail stages (they write As/Bs)
  asm volatile("s_waitcnt vmcnt(0)" ::: "memory");
  __builtin_amdgcn_s_barrier();

  // C/D frag layout: col = lane&15, row = (lane>>4)*4 + reg
  const int orow = (l >> 4) * 4;
  const int ocol = l & 15;
  if (OUT_BF16) {
    uint16_t* C = (uint16_t*)Cout;
    char* eb = (char*)&As[0][0][0] + (size_t)w * 4096;   // wave-private 4KB
    const int rr0 = l >> 3;
    const int cc0 = (l & 7) * 8;
#pragma unroll
    for (int mm = 0; mm < 4; ++mm) {
#pragma unroll
      for (int nn = 0; nn < 4; ++nn)
#pragma unroll
        for (int r2 = 0; r2 < 4; ++r2) {
          int rrow = orow + r2;
          int byo = ((rrow * 64 + nn * 16 + ocol) * 2) ^ ((rrow & 7) << 4);
          *(uint16_t*)(eb + byo) = f2bf(acc[mm][nn][r2]);
        }
#pragma unroll
      for (int p = 0; p < 2; ++p) {
        int rrow = rr0 + p * 8;
        int byo = ((rrow * 64 + cc0) * 2) ^ ((rrow & 7) << 4);
        short8 vvv = *(const short8*)(eb + byo);
        *(short8*)(&C[(m0 + wm * 64 + mm * 16 + rrow) * N + n0 + wn * 64 + cc0]) = vvv;
      }
    }
  } else {
    float* C = (float*)Cout;
    float* eb = (float*)&As[0][0][0] + (size_t)w * 1024;  // wave-private 4KB
    const int rr0 = l >> 4;
    const int cc0 = (l & 15) * 4;
    float4 bias4 = make_float4(0.f, 0.f, 0.f, 0.f);
    if (bias) bias4 = *(const float4*)(bias + n0 + wn * 64 + cc0);
#pragma unroll
    for (int mm = 0; mm < 4; ++mm) {
#pragma unroll
      for (int nn = 0; nn < 4; ++nn)
#pragma unroll
        for (int r2 = 0; r2 < 4; ++r2)
          eb[(orow + r2) * 64 + nn * 16 + ocol] = acc[mm][nn][r2];
#pragma unroll
      for (int p = 0; p < 4; ++p) {
        int rrow = rr0 + p * 4;
        float4 vvv = *(const float4*)(eb + rrow * 64 + cc0);
        vvv.x += bias4.x; vvv.y += bias4.y; vvv.z += bias4.z; vvv.w += bias4.w;
        *(float4*)(&C[(m0 + wm * 64 + mm * 16 + rrow) * N + n0 + wn * 64 + cc0]) = vvv;
      }
    }
  }
}

// ---------------- per-token 6-head attention, 16 lanes per token ----------------
__global__ __launch_bounds__(256)
void k_attn(const uint16_t* __restrict__ qkv, uint16_t* __restrict__ outp) {
  const int wid = blockIdx.x * 4 + (threadIdx.x >> 6);
  const int l = threadIdx.x & 63;
  const int sub = l >> 4;
  const int i = l & 15;
  const int token = wid * 4 + sub;
  const uint16_t* row = qkv + (long)token * 2304 + i * 8;

  short8 kv[6];
  float qf[6][8];
#pragma unroll
  for (int h = 0; h < 6; ++h) {
    short8 qv = *(const short8*)(row + h * 128);
    kv[h] = *(const short8*)(row + 768 + h * 128);
#pragma unroll
    for (int e = 0; e < 8; ++e) qf[h][e] = bfu(qv[e]);
  }

  float s[36];
#pragma unroll
  for (int g = 0; g < 6; ++g) {
    float kf[8];
#pragma unroll
    for (int e = 0; e < 8; ++e) kf[e] = bfu(kv[g][e]);
#pragma unroll
    for (int h = 0; h < 6; ++h) {
      float a = 0.f;
#pragma unroll
      for (int e = 0; e < 8; ++e) a += qf[h][e] * kf[e];
      s[h * 6 + g] = a;
    }
  }

#pragma unroll
  for (int off = 8; off > 0; off >>= 1)
#pragma unroll
    for (int j = 0; j < 36; ++j)
      s[j] += __shfl_xor(s[j], off, 64);

  const float scale = 0.088388347648318447f;  // 128^-0.5
  float p[36];
#pragma unroll
  for (int h = 0; h < 6; ++h) {
    float mx = s[h * 6];
#pragma unroll
    for (int g = 1; g < 6; ++g) mx = fmaxf(mx, s[h * 6 + g]);
    float sum = 0.f;
#pragma unroll
    for (int g = 0; g < 6; ++g) {
      float e = __expf((s[h * 6 + g] - mx) * scale);
      p[h * 6 + g] = e; sum += e;
    }
    float inv = 1.f / sum;
#pragma unroll
    for (int g = 0; g < 6; ++g) p[h * 6 + g] *= inv;
  }

  float o[6][8];
#pragma unroll
  for (int h = 0; h < 6; ++h)
#pragma unroll
    for (int e = 0; e < 8; ++e) o[h][e] = 0.f;
#pragma unroll
  for (int g = 0; g < 6; ++g) {
    short8 vv = *(const short8*)(row + 1536 + g * 128);
    float vf[8];
#pragma unroll
    for (int e = 0; e < 8; ++e) vf[e] = bfu(vv[e]);
#pragma unroll
    for (int h = 0; h < 6; ++h)
#pragma unroll
      for (int e = 0; e < 8; ++e) o[h][e] += p[h * 6 + g] * vf[e];
  }

  const int b = token >> 12, nn = token & 4095;
#pragma unroll
  for (int h = 0; h < 6; ++h) {
    short8 ov;
#pragma unroll
    for (int e = 0; e < 8; ++e) ov[e] = (short)f2bf(o[h][e]);
    *(short8*)(outp + ((long)(b * 6 + h) * 4096 + nn) * 128 + i * 8) = ov;
  }
}

extern "C" void kernel_launch(void* const* d_in, const int* in_sizes, int n_in,
                              void* d_out, int out_size, void* d_ws, size_t ws_size,
                              hipStream_t stream) {
  const float* x      = (const float*)d_in[0];
  const float* w_qkv  = (const float*)d_in[1];
  const float* w_proj = (const float*)d_in[2];
  const float* b_proj = (const float*)d_in[3];
  float* out = (float*)d_out;

  const int Cc = 768, C3 = 2304;
  const int Mtok = in_sizes[0] / Cc;  // 32768

  char* ws = (char*)d_ws;
  uint16_t* x_bf   = (uint16_t*)ws;                            // 50,331,648 B
  uint16_t* att_bf = x_bf;                                     // reuse (x_bf dead after GEMM1)
  uint16_t* qkv_bf = (uint16_t*)(ws + 50331648);               // 150,994,944 B
  uint16_t* wqkvT  = (uint16_t*)(ws + 50331648 + 150994944);   // 3,538,944 B
  uint16_t* wprojT = (uint16_t*)(ws + 50331648 + 150994944 + 3538944); // 1,179,648 B

  hipLaunchKernelGGL(k_prep, dim3(2048 + 432 + 144), dim3(256), 0, stream,
                     x, x_bf, Mtok * Cc / 4, w_qkv, wqkvT, w_proj, wprojT);

  // GEMM1: 256 x 18 = 4608 blocks = 9.0 exact rounds at 2 blocks/CU
  hipLaunchKernelGGL((k_gemm128<1>), dim3((Mtok / 128) * (C3 / 128)), dim3(256), 0, stream,
                     x_bf, wqkvT, (void*)qkv_bf, (const float*)nullptr, Mtok, C3, Cc, C3 / 128);

  hipLaunchKernelGGL(k_attn, dim3(Mtok / 16), dim3(256), 0, stream, qkv_bf, att_bf);

  // GEMM2: 256 x 6 = 1536 blocks = 3.0 exact rounds at 2 blocks/CU
  hipLaunchKernelGGL((k_gemm128<0>), dim3((Mtok / 128) * (Cc / 128)), dim3(256), 0, stream,
                     att_bf, wprojT, (void*)out, b_proj, Mtok, Cc, Cc, Cc / 128);
}